// Round 9
// baseline (143.812 us; speedup 1.0000x reference)
//
#include <hip/hip_runtime.h>

#define BATCH 131072
#define XDIM 260          // 256 state + 4 goal
#define SDIM 256
#define HID 256
#define HHID 128
#define ODIM 128

typedef __attribute__((ext_vector_type(8))) short short8;     // raw 16B moves
typedef __attribute__((ext_vector_type(4))) short short4v;
typedef __attribute__((ext_vector_type(4))) float floatx4;    // MFMA accum
typedef __attribute__((ext_vector_type(8))) _Float16 half8;   // f16 MFMA frag

// fp32 -> fp16 RTNE (hardware v_cvt_f16_f32). All values well inside fp16
// range (|x|<6, |W|<0.2, |h|<6, |t|<2). fp16 quantization ~8x finer than
// bf16 -> expected absmax ~3e-4 vs 4.22e-3 threshold.
__device__ __forceinline__ short f2h(float f) {
    union { _Float16 h; short s; } u;
    u.h = (_Float16)f;
    return u.s;
}

// ---------------------------------------------------------------------------
// prep: W0T[n][k]=fp16(W0[k][n]) (256x256), W1T[g][n][k] (4x128x256),
//       W2T[g][n][k] (4x128x128); zero bucket cursors.  (R2 structure)
// ---------------------------------------------------------------------------
__global__ void prep_kernel(const float* __restrict__ W0, const float* __restrict__ W1,
                            const float* __restrict__ W2, short* __restrict__ W0T,
                            short* __restrict__ W1T, short* __restrict__ W2T,
                            int* __restrict__ cursor) {
    int i = blockIdx.x * 256 + threadIdx.x;   // grid 512*256 = 131072
    if (i < 4) cursor[i] = 0;
    if (i < 65536) {            // W0T
        int n = i >> 8, k = i & 255;
        W0T[i] = f2h(W0[k * HID + n]);
    }
    if (i < 131072) {           // W1T
        int g = i >> 15, r = i & 32767;
        int n = r >> 8, k = r & 255;
        W1T[i] = f2h(W1[(g * SDIM + k) * HHID + n]);
    }
    if (i < 65536) {            // W2T
        int g = i >> 14, r = i & 16383;
        int n = r >> 7, k = r & 127;
        W2T[i] = f2h(W2[(g * HHID + k) * ODIM + n]);
    }
}

// ---------------------------------------------------------------------------
// bucket: per-row argmax(goal) -> counting sort (hierarchical; R2-proven).
// goal read in exact fp32 -> argmax identical to reference.
// ---------------------------------------------------------------------------
__global__ void bucket_kernel(const float* __restrict__ x, int* __restrict__ cursor,
                              int* __restrict__ perm) {
    __shared__ int lhist[4];
    __shared__ int lbase[4];
    const int tid = threadIdx.x;
    if (tid < 4) lhist[tid] = 0;
    __syncthreads();

    const int row = blockIdx.x * 256 + tid;
    const float4 gv = *reinterpret_cast<const float4*>(x + (size_t)row * XDIM + SDIM);
    int gi = 0; float best = gv.x;
    if (gv.y > best) { best = gv.y; gi = 1; }   // strict > keeps first max (jnp.argmax)
    if (gv.z > best) { best = gv.z; gi = 2; }
    if (gv.w > best) { best = gv.w; gi = 3; }

    const int lpos = atomicAdd(&lhist[gi], 1);
    __syncthreads();
    if (tid < 4) lbase[tid] = atomicAdd(&cursor[tid], lhist[tid]);
    __syncthreads();
    perm[gi * BATCH + lbase[gi] + lpos] = row;
}

// ---------------------------------------------------------------------------
// K1: h = LeakyReLU(LN(state @ W0 + b0)) -> fp16, stored into H (aliases d_out)
// EXACTLY R7's kernel (passed both checks, 91us) with ONLY the dtype flipped
// to fp16. Epilogue = R2's proven serial-shfl LN + scalar stores (the R6/R8
// rebuilt epilogue is quarantined: dtype-independent ~3e-3 corruption +
// cross-replay drift). One-variable experiment: if absmax ~3e-4, R7's 2.8e-3
// was quantization and we gain ~10x margin; if ~2.8e-3 persists, the
// sched_barrier staging is convicted and gets reverted next round.
// ---------------------------------------------------------------------------
__global__ __launch_bounds__(256, 2) void k1_gemm_ln(
        const float* __restrict__ x, const float* __restrict__ b0,
        const float* __restrict__ gamma, const float* __restrict__ beta,
        const short* __restrict__ W0T, short* __restrict__ H) {
    __shared__ __align__(16) short a_lds[64][264];   // 256 + 8 pad
    __shared__ float psum[64][4];
    __shared__ float psq[64][4];
    __shared__ float mu_s[64];
    __shared__ float rs_s[64];

    const int tid = threadIdx.x;
    const int lane = tid & 63;
    const int w = tid >> 6;
    const int m0 = blockIdx.x * 64;

    // ---- stage x(state) fp32 -> fp16 LDS; 2 batches of 8 in-flight float4s
    #pragma unroll
    for (int half = 0; half < 2; ++half) {
        float4 v[8];
        #pragma unroll
        for (int c = 0; c < 8; ++c) {
            int s = (half * 8 + c) * 256 + tid;     // float4 slot, 64 rows x 64 slots
            int row = s >> 6;
            int k4 = (s & 63) << 2;
            v[c] = *reinterpret_cast<const float4*>(x + (size_t)(m0 + row) * XDIM + k4);
        }
        __builtin_amdgcn_sched_barrier(0);   // keep all 8 loads issued before any use
        #pragma unroll
        for (int c = 0; c < 8; ++c) {
            int s = (half * 8 + c) * 256 + tid;
            int row = s >> 6;
            int k4 = (s & 63) << 2;
            short4v sv;
            sv.x = f2h(v[c].x); sv.y = f2h(v[c].y); sv.z = f2h(v[c].z); sv.w = f2h(v[c].w);
            *reinterpret_cast<short4v*>(&a_lds[row][k4]) = sv;
        }
    }
    __syncthreads();

    const int q = lane >> 4;
    const int l15 = lane & 15;

    floatx4 acc[4][4] = {};                    // [mi][ni], rows mi*16+q*4+r, cols w*64+ni*16+l15
    const short* Bw = W0T + (size_t)(w << 6) * HID;

    for (int k0 = 0; k0 < 256; k0 += 32) {
        half8 af[4], bf[4];
        #pragma unroll
        for (int mi = 0; mi < 4; ++mi)
            af[mi] = *reinterpret_cast<const half8*>(&a_lds[mi * 16 + l15][k0 + q * 8]);
        #pragma unroll
        for (int ni = 0; ni < 4; ++ni)
            bf[ni] = *reinterpret_cast<const half8*>(Bw + (size_t)(ni * 16 + l15) * HID + k0 + q * 8);
        #pragma unroll
        for (int mi = 0; mi < 4; ++mi)
            #pragma unroll
            for (int ni = 0; ni < 4; ++ni)
                acc[mi][ni] = __builtin_amdgcn_mfma_f32_16x16x32_f16(af[mi], bf[ni], acc[mi][ni], 0, 0, 0);
    }

    // ---- + b0, LN stats (shfl_xor over the 16 lanes sharing a row, then LDS cross-wave)
    float bias[4], gm[4], bt[4];
    #pragma unroll
    for (int ni = 0; ni < 4; ++ni) {
        int col = (w << 6) + ni * 16 + l15;
        bias[ni] = b0[col]; gm[ni] = gamma[col]; bt[ni] = beta[col];
    }
    #pragma unroll
    for (int mi = 0; mi < 4; ++mi) {
        #pragma unroll
        for (int r = 0; r < 4; ++r) {
            float s = 0.f, ss = 0.f;
            #pragma unroll
            for (int ni = 0; ni < 4; ++ni) {
                float v = acc[mi][ni][r] + bias[ni];
                acc[mi][ni][r] = v;
                s += v; ss += v * v;
            }
            #pragma unroll
            for (int off = 1; off < 16; off <<= 1) {
                s  += __shfl_xor(s,  off, 64);
                ss += __shfl_xor(ss, off, 64);
            }
            if (l15 == 0) {
                int row = mi * 16 + q * 4 + r;
                psum[row][w] = s;
                psq[row][w]  = ss;
            }
        }
    }
    __syncthreads();
    if (tid < 64) {
        float s  = psum[tid][0] + psum[tid][1] + psum[tid][2] + psum[tid][3];
        float ss = psq[tid][0]  + psq[tid][1]  + psq[tid][2]  + psq[tid][3];
        float mu = s * (1.f / 256.f);
        float var = ss * (1.f / 256.f) - mu * mu;
        mu_s[tid] = mu;
        rs_s[tid] = rsqrtf(var + 1e-5f);
    }
    __syncthreads();

    // ---- normalize + leaky + store fp16 (R2-proven scalar store epilogue)
    #pragma unroll
    for (int mi = 0; mi < 4; ++mi) {
        #pragma unroll
        for (int r = 0; r < 4; ++r) {
            int row = mi * 16 + q * 4 + r;
            float mu = mu_s[row], rs = rs_s[row];
            short* dst = H + (size_t)(m0 + row) * HID + (w << 6) + l15;
            #pragma unroll
            for (int ni = 0; ni < 4; ++ni) {
                float v = (acc[mi][ni][r] - mu) * rs * gm[ni] + bt[ni];
                v = (v >= 0.f) ? v : 0.1f * v;
                dst[ni * 16] = f2h(v);
            }
        }
    }
}

// ---------------------------------------------------------------------------
// K2: per (goal g, 64-row tile): t = relu(h @ W1[g] + b1[g]); out = t @ W2[g] + b2[g]
// H aliases out row-in-place (R2-proven race-free). Structure untouched;
// dtype fp16.
// ---------------------------------------------------------------------------
__global__ __launch_bounds__(256, 2) void k2_heads(
        const short* H, const short* __restrict__ W1T, const short* __restrict__ W2T,
        const float* __restrict__ b1, const float* __restrict__ b2,
        const int* __restrict__ cursor, const int* __restrict__ perm,
        float* out) {
    const int g = blockIdx.y;
    const int t = blockIdx.x;
    const int cnt = cursor[g];
    if (t * 64 >= cnt) return;

    __shared__ __align__(16) short a_lds[64][264];
    __shared__ __align__(16) short t_lds[64][136];
    __shared__ int rows_s[64];

    const int tid = threadIdx.x;
    const int lane = tid & 63;
    const int w = tid >> 6;
    const int* pg = perm + (size_t)g * BATCH;

    if (tid < 64) {
        int idx = t * 64 + tid;
        rows_s[tid] = pg[idx < cnt ? idx : cnt - 1];
    }
    __syncthreads();

    // ---- gather h rows (fp16), coalesced 16B/lane
    #pragma unroll
    for (int c = 0; c < 8; ++c) {
        int s = c * 256 + tid;                 // 16B slot, 64 rows x 32 slots
        int row = s >> 5;
        int k8 = (s & 31) << 3;
        short8 v = *reinterpret_cast<const short8*>(H + (size_t)rows_s[row] * HID + k8);
        *reinterpret_cast<short8*>(&a_lds[row][k8]) = v;
    }
    __syncthreads();

    const int q = lane >> 4;
    const int l15 = lane & 15;

    // ---- GEMM1: 64x128, K=256; wave w owns cols [w*32, w*32+32)
    floatx4 acc1[4][2] = {};
    const short* B1 = W1T + (size_t)(g * HHID + (w << 5)) * HID;
    for (int k0 = 0; k0 < 256; k0 += 32) {
        half8 af[4], bf[2];
        #pragma unroll
        for (int mi = 0; mi < 4; ++mi)
            af[mi] = *reinterpret_cast<const half8*>(&a_lds[mi * 16 + l15][k0 + q * 8]);
        #pragma unroll
        for (int ni = 0; ni < 2; ++ni)
            bf[ni] = *reinterpret_cast<const half8*>(B1 + (size_t)(ni * 16 + l15) * HID + k0 + q * 8);
        #pragma unroll
        for (int mi = 0; mi < 4; ++mi)
            #pragma unroll
            for (int ni = 0; ni < 2; ++ni)
                acc1[mi][ni] = __builtin_amdgcn_mfma_f32_16x16x32_f16(af[mi], bf[ni], acc1[mi][ni], 0, 0, 0);
    }
    // bias + relu -> t_lds (fp16)
    #pragma unroll
    for (int ni = 0; ni < 2; ++ni) {
        int col = (w << 5) + ni * 16 + l15;
        float bb = b1[g * HHID + col];
        #pragma unroll
        for (int mi = 0; mi < 4; ++mi)
            #pragma unroll
            for (int r = 0; r < 4; ++r) {
                int row = mi * 16 + q * 4 + r;
                float v = acc1[mi][ni][r] + bb;
                t_lds[row][col] = f2h(v > 0.f ? v : 0.f);
            }
    }
    __syncthreads();

    // ---- GEMM2: 64x128, K=128
    floatx4 acc2[4][2] = {};
    const short* B2 = W2T + (size_t)(g * ODIM + (w << 5)) * HHID;
    for (int k0 = 0; k0 < 128; k0 += 32) {
        half8 af[4], bf[2];
        #pragma unroll
        for (int mi = 0; mi < 4; ++mi)
            af[mi] = *reinterpret_cast<const half8*>(&t_lds[mi * 16 + l15][k0 + q * 8]);
        #pragma unroll
        for (int ni = 0; ni < 2; ++ni)
            bf[ni] = *reinterpret_cast<const half8*>(B2 + (size_t)(ni * 16 + l15) * HHID + k0 + q * 8);
        #pragma unroll
        for (int mi = 0; mi < 4; ++mi)
            #pragma unroll
            for (int ni = 0; ni < 2; ++ni)
                acc2[mi][ni] = __builtin_amdgcn_mfma_f32_16x16x32_f16(af[mi], bf[ni], acc2[mi][ni], 0, 0, 0);
    }
    // bias + scatter out (fp32)
    #pragma unroll
    for (int ni = 0; ni < 2; ++ni) {
        int col = (w << 5) + ni * 16 + l15;
        float bb = b2[g * ODIM + col];
        #pragma unroll
        for (int mi = 0; mi < 4; ++mi)
            #pragma unroll
            for (int r = 0; r < 4; ++r) {
                int row = mi * 16 + q * 4 + r;
                int idx = t * 64 + row;
                if (idx < cnt)
                    out[(size_t)rows_s[row] * ODIM + col] = acc2[mi][ni][r] + bb;
            }
    }
}

// ---------------------------------------------------------------------------
// workspace layout (2.62 MB):
//   [0, 131072)            W0T fp16
//   [131072, 393216)       W1T fp16
//   [393216, 524288)       W2T fp16
//   [524288, 524304)       cursor (padded to 1024)
//   [525312, 2622464)      perm (4 x 131072 int)
// h (fp16, 64 MB) lives in d_out (same byte footprint as the fp32 output).
// ---------------------------------------------------------------------------
extern "C" void kernel_launch(void* const* d_in, const int* in_sizes, int n_in,
                              void* d_out, int out_size, void* d_ws, size_t ws_size,
                              hipStream_t stream) {
    const float* x     = (const float*)d_in[0];
    const float* W0    = (const float*)d_in[1];
    const float* b0    = (const float*)d_in[2];
    const float* gamma = (const float*)d_in[3];
    const float* beta  = (const float*)d_in[4];
    const float* W1    = (const float*)d_in[5];
    const float* b1    = (const float*)d_in[6];
    const float* W2    = (const float*)d_in[7];
    const float* b2    = (const float*)d_in[8];

    char* ws = (char*)d_ws;
    short* W0T  = (short*)(ws);
    short* W1T  = (short*)(ws + 131072);
    short* W2T  = (short*)(ws + 393216);
    int* cursor = (int*)(ws + 524288);
    int* perm   = (int*)(ws + 525312);
    short* H    = (short*)d_out;           // fp16 h aliases the fp32 output buffer
    float* out  = (float*)d_out;

    prep_kernel<<<512, 256, 0, stream>>>(W0, W1, W2, W0T, W1T, W2T, cursor);
    bucket_kernel<<<512, 256, 0, stream>>>(x, cursor, perm);
    k1_gemm_ln<<<BATCH / 64, 256, 0, stream>>>(x, b0, gamma, beta, W0T, H);
    k2_heads<<<dim3(BATCH / 64, 4), 256, 0, stream>>>(H, W1T, W2T, b1, b2, cursor, perm, out);
}

// Round 10
// 133.882 us; speedup vs baseline: 1.0742x; 1.0742x over previous
//
#include <hip/hip_runtime.h>

#define BATCH 131072
#define XDIM 260          // 256 state + 4 goal
#define SDIM 256
#define HID 256
#define HHID 128
#define ODIM 128

typedef __attribute__((ext_vector_type(8))) short short8;     // raw 16B moves
typedef __attribute__((ext_vector_type(4))) short short4v;
typedef __attribute__((ext_vector_type(4))) float floatx4;    // MFMA accum
typedef __attribute__((ext_vector_type(8))) _Float16 half8;   // f16 MFMA frag

// fp32 -> fp16 RTNE (hardware v_cvt_f16_f32). All values well inside fp16
// range (|x|<6, |W|<0.2, |h|<6, |t|<2). Proven absmax 9.77e-4 (R9) vs
// 4.22e-3 threshold.
__device__ __forceinline__ short f2h(float f) {
    union { _Float16 h; short s; } u;
    u.h = (_Float16)f;
    return u.s;
}

// ---------------------------------------------------------------------------
// prep: W0T[n][k]=fp16(W0[k][n]) (256x256), W1T[g][n][k] (4x128x256),
//       W2T[g][n][k] (4x128x128); zero bucket cursors.  (R9-proven)
// ---------------------------------------------------------------------------
__global__ void prep_kernel(const float* __restrict__ W0, const float* __restrict__ W1,
                            const float* __restrict__ W2, short* __restrict__ W0T,
                            short* __restrict__ W1T, short* __restrict__ W2T,
                            int* __restrict__ cursor) {
    int i = blockIdx.x * 256 + threadIdx.x;   // grid 512*256 = 131072
    if (i < 4) cursor[i] = 0;
    if (i < 65536) {            // W0T
        int n = i >> 8, k = i & 255;
        W0T[i] = f2h(W0[k * HID + n]);
    }
    if (i < 131072) {           // W1T
        int g = i >> 15, r = i & 32767;
        int n = r >> 8, k = r & 255;
        W1T[i] = f2h(W1[(g * SDIM + k) * HHID + n]);
    }
    if (i < 65536) {            // W2T
        int g = i >> 14, r = i & 16383;
        int n = r >> 7, k = r & 127;
        W2T[i] = f2h(W2[(g * HHID + k) * ODIM + n]);
    }
}

// ---------------------------------------------------------------------------
// bucket: per-row argmax(goal) -> counting sort (hierarchical; R2-proven).
// goal read in exact fp32 -> argmax identical to reference.
// ---------------------------------------------------------------------------
__global__ void bucket_kernel(const float* __restrict__ x, int* __restrict__ cursor,
                              int* __restrict__ perm) {
    __shared__ int lhist[4];
    __shared__ int lbase[4];
    const int tid = threadIdx.x;
    if (tid < 4) lhist[tid] = 0;
    __syncthreads();

    const int row = blockIdx.x * 256 + tid;
    const float4 gv = *reinterpret_cast<const float4*>(x + (size_t)row * XDIM + SDIM);
    int gi = 0; float best = gv.x;
    if (gv.y > best) { best = gv.y; gi = 1; }   // strict > keeps first max (jnp.argmax)
    if (gv.z > best) { best = gv.z; gi = 2; }
    if (gv.w > best) { best = gv.w; gi = 3; }

    const int lpos = atomicAdd(&lhist[gi], 1);
    __syncthreads();
    if (tid < 4) lbase[tid] = atomicAdd(&cursor[tid], lhist[tid]);
    __syncthreads();
    perm[gi * BATCH + lbase[gi] + lpos] = row;
}

// ---------------------------------------------------------------------------
// K1: h = LeakyReLU(LN(state @ W0 + b0)) -> fp16, stored into H (aliases d_out)
// R9's kernel (passed, absmax 9.77e-4) with ONE delta: __launch_bounds__
// (256, 4). gfx950's unified VGPR/AGPR file puts R9 at ~132 combined regs
// (68 VGPR + 64 AGPR acc) -- 4 past the 128-reg cliff for 4 waves/SIMD.
// The bound forces the allocator under 128 combined -> 4 blocks/CU
// guaranteed (occupancy 28% -> ~50%), at worst a few cheap scratch spills
// in the staging phase. k1 is latency-bound (VALU 15%, MFMA 6.5%, 2 TB/s
// effective): resident-wave count is the remaining proven lever.
// ---------------------------------------------------------------------------
__global__ __launch_bounds__(256, 4) void k1_gemm_ln(
        const float* __restrict__ x, const float* __restrict__ b0,
        const float* __restrict__ gamma, const float* __restrict__ beta,
        const short* __restrict__ W0T, short* __restrict__ H) {
    __shared__ __align__(16) short a_lds[64][264];   // 256 + 8 pad
    __shared__ float psum[64][4];
    __shared__ float psq[64][4];
    __shared__ float mu_s[64];
    __shared__ float rs_s[64];

    const int tid = threadIdx.x;
    const int lane = tid & 63;
    const int w = tid >> 6;
    const int m0 = blockIdx.x * 64;

    // ---- stage x(state) fp32 -> fp16 LDS; 2 batches of 8 in-flight float4s
    #pragma unroll
    for (int half = 0; half < 2; ++half) {
        float4 v[8];
        #pragma unroll
        for (int c = 0; c < 8; ++c) {
            int s = (half * 8 + c) * 256 + tid;     // float4 slot, 64 rows x 64 slots
            int row = s >> 6;
            int k4 = (s & 63) << 2;
            v[c] = *reinterpret_cast<const float4*>(x + (size_t)(m0 + row) * XDIM + k4);
        }
        __builtin_amdgcn_sched_barrier(0);   // keep all 8 loads issued before any use
        #pragma unroll
        for (int c = 0; c < 8; ++c) {
            int s = (half * 8 + c) * 256 + tid;
            int row = s >> 6;
            int k4 = (s & 63) << 2;
            short4v sv;
            sv.x = f2h(v[c].x); sv.y = f2h(v[c].y); sv.z = f2h(v[c].z); sv.w = f2h(v[c].w);
            *reinterpret_cast<short4v*>(&a_lds[row][k4]) = sv;
        }
    }
    __syncthreads();

    const int q = lane >> 4;
    const int l15 = lane & 15;

    floatx4 acc[4][4] = {};                    // [mi][ni], rows mi*16+q*4+r, cols w*64+ni*16+l15
    const short* Bw = W0T + (size_t)(w << 6) * HID;

    for (int k0 = 0; k0 < 256; k0 += 32) {
        half8 af[4], bf[4];
        #pragma unroll
        for (int mi = 0; mi < 4; ++mi)
            af[mi] = *reinterpret_cast<const half8*>(&a_lds[mi * 16 + l15][k0 + q * 8]);
        #pragma unroll
        for (int ni = 0; ni < 4; ++ni)
            bf[ni] = *reinterpret_cast<const half8*>(Bw + (size_t)(ni * 16 + l15) * HID + k0 + q * 8);
        #pragma unroll
        for (int mi = 0; mi < 4; ++mi)
            #pragma unroll
            for (int ni = 0; ni < 4; ++ni)
                acc[mi][ni] = __builtin_amdgcn_mfma_f32_16x16x32_f16(af[mi], bf[ni], acc[mi][ni], 0, 0, 0);
    }

    // ---- + b0, LN stats (shfl_xor over the 16 lanes sharing a row, then LDS cross-wave)
    float bias[4], gm[4], bt[4];
    #pragma unroll
    for (int ni = 0; ni < 4; ++ni) {
        int col = (w << 6) + ni * 16 + l15;
        bias[ni] = b0[col]; gm[ni] = gamma[col]; bt[ni] = beta[col];
    }
    #pragma unroll
    for (int mi = 0; mi < 4; ++mi) {
        #pragma unroll
        for (int r = 0; r < 4; ++r) {
            float s = 0.f, ss = 0.f;
            #pragma unroll
            for (int ni = 0; ni < 4; ++ni) {
                float v = acc[mi][ni][r] + bias[ni];
                acc[mi][ni][r] = v;
                s += v; ss += v * v;
            }
            #pragma unroll
            for (int off = 1; off < 16; off <<= 1) {
                s  += __shfl_xor(s,  off, 64);
                ss += __shfl_xor(ss, off, 64);
            }
            if (l15 == 0) {
                int row = mi * 16 + q * 4 + r;
                psum[row][w] = s;
                psq[row][w]  = ss;
            }
        }
    }
    __syncthreads();
    if (tid < 64) {
        float s  = psum[tid][0] + psum[tid][1] + psum[tid][2] + psum[tid][3];
        float ss = psq[tid][0]  + psq[tid][1]  + psq[tid][2]  + psq[tid][3];
        float mu = s * (1.f / 256.f);
        float var = ss * (1.f / 256.f) - mu * mu;
        mu_s[tid] = mu;
        rs_s[tid] = rsqrtf(var + 1e-5f);
    }
    __syncthreads();

    // ---- normalize + leaky + store fp16 (R2-proven scalar store epilogue)
    #pragma unroll
    for (int mi = 0; mi < 4; ++mi) {
        #pragma unroll
        for (int r = 0; r < 4; ++r) {
            int row = mi * 16 + q * 4 + r;
            float mu = mu_s[row], rs = rs_s[row];
            short* dst = H + (size_t)(m0 + row) * HID + (w << 6) + l15;
            #pragma unroll
            for (int ni = 0; ni < 4; ++ni) {
                float v = (acc[mi][ni][r] - mu) * rs * gm[ni] + bt[ni];
                v = (v >= 0.f) ? v : 0.1f * v;
                dst[ni * 16] = f2h(v);
            }
        }
    }
}

// ---------------------------------------------------------------------------
// K2: per (goal g, 64-row tile): t = relu(h @ W1[g] + b1[g]); out = t @ W2[g] + b2[g]
// H aliases out row-in-place (R2-proven race-free). Untouched control.
// ---------------------------------------------------------------------------
__global__ __launch_bounds__(256, 2) void k2_heads(
        const short* H, const short* __restrict__ W1T, const short* __restrict__ W2T,
        const float* __restrict__ b1, const float* __restrict__ b2,
        const int* __restrict__ cursor, const int* __restrict__ perm,
        float* out) {
    const int g = blockIdx.y;
    const int t = blockIdx.x;
    const int cnt = cursor[g];
    if (t * 64 >= cnt) return;

    __shared__ __align__(16) short a_lds[64][264];
    __shared__ __align__(16) short t_lds[64][136];
    __shared__ int rows_s[64];

    const int tid = threadIdx.x;
    const int lane = tid & 63;
    const int w = tid >> 6;
    const int* pg = perm + (size_t)g * BATCH;

    if (tid < 64) {
        int idx = t * 64 + tid;
        rows_s[tid] = pg[idx < cnt ? idx : cnt - 1];
    }
    __syncthreads();

    // ---- gather h rows (fp16), coalesced 16B/lane
    #pragma unroll
    for (int c = 0; c < 8; ++c) {
        int s = c * 256 + tid;                 // 16B slot, 64 rows x 32 slots
        int row = s >> 5;
        int k8 = (s & 31) << 3;
        short8 v = *reinterpret_cast<const short8*>(H + (size_t)rows_s[row] * HID + k8);
        *reinterpret_cast<short8*>(&a_lds[row][k8]) = v;
    }
    __syncthreads();

    const int q = lane >> 4;
    const int l15 = lane & 15;

    // ---- GEMM1: 64x128, K=256; wave w owns cols [w*32, w*32+32)
    floatx4 acc1[4][2] = {};
    const short* B1 = W1T + (size_t)(g * HHID + (w << 5)) * HID;
    for (int k0 = 0; k0 < 256; k0 += 32) {
        half8 af[4], bf[2];
        #pragma unroll
        for (int mi = 0; mi < 4; ++mi)
            af[mi] = *reinterpret_cast<const half8*>(&a_lds[mi * 16 + l15][k0 + q * 8]);
        #pragma unroll
        for (int ni = 0; ni < 2; ++ni)
            bf[ni] = *reinterpret_cast<const half8*>(B1 + (size_t)(ni * 16 + l15) * HID + k0 + q * 8);
        #pragma unroll
        for (int mi = 0; mi < 4; ++mi)
            #pragma unroll
            for (int ni = 0; ni < 2; ++ni)
                acc1[mi][ni] = __builtin_amdgcn_mfma_f32_16x16x32_f16(af[mi], bf[ni], acc1[mi][ni], 0, 0, 0);
    }
    // bias + relu -> t_lds (fp16)
    #pragma unroll
    for (int ni = 0; ni < 2; ++ni) {
        int col = (w << 5) + ni * 16 + l15;
        float bb = b1[g * HHID + col];
        #pragma unroll
        for (int mi = 0; mi < 4; ++mi)
            #pragma unroll
            for (int r = 0; r < 4; ++r) {
                int row = mi * 16 + q * 4 + r;
                float v = acc1[mi][ni][r] + bb;
                t_lds[row][col] = f2h(v > 0.f ? v : 0.f);
            }
    }
    __syncthreads();

    // ---- GEMM2: 64x128, K=128
    floatx4 acc2[4][2] = {};
    const short* B2 = W2T + (size_t)(g * ODIM + (w << 5)) * HHID;
    for (int k0 = 0; k0 < 128; k0 += 32) {
        half8 af[4], bf[2];
        #pragma unroll
        for (int mi = 0; mi < 4; ++mi)
            af[mi] = *reinterpret_cast<const half8*>(&t_lds[mi * 16 + l15][k0 + q * 8]);
        #pragma unroll
        for (int ni = 0; ni < 2; ++ni)
            bf[ni] = *reinterpret_cast<const half8*>(B2 + (size_t)(ni * 16 + l15) * HHID + k0 + q * 8);
        #pragma unroll
        for (int mi = 0; mi < 4; ++mi)
            #pragma unroll
            for (int ni = 0; ni < 2; ++ni)
                acc2[mi][ni] = __builtin_amdgcn_mfma_f32_16x16x32_f16(af[mi], bf[ni], acc2[mi][ni], 0, 0, 0);
    }
    // bias + scatter out (fp32)
    #pragma unroll
    for (int ni = 0; ni < 2; ++ni) {
        int col = (w << 5) + ni * 16 + l15;
        float bb = b2[g * ODIM + col];
        #pragma unroll
        for (int mi = 0; mi < 4; ++mi)
            #pragma unroll
            for (int r = 0; r < 4; ++r) {
                int row = mi * 16 + q * 4 + r;
                int idx = t * 64 + row;
                if (idx < cnt)
                    out[(size_t)rows_s[row] * ODIM + col] = acc2[mi][ni][r] + bb;
            }
    }
}

// ---------------------------------------------------------------------------
// workspace layout (2.62 MB):
//   [0, 131072)            W0T fp16
//   [131072, 393216)       W1T fp16
//   [393216, 524288)       W2T fp16
//   [524288, 524304)       cursor (padded to 1024)
//   [525312, 2622464)      perm (4 x 131072 int)
// h (fp16, 64 MB) lives in d_out (same byte footprint as the fp32 output).
// ---------------------------------------------------------------------------
extern "C" void kernel_launch(void* const* d_in, const int* in_sizes, int n_in,
                              void* d_out, int out_size, void* d_ws, size_t ws_size,
                              hipStream_t stream) {
    const float* x     = (const float*)d_in[0];
    const float* W0    = (const float*)d_in[1];
    const float* b0    = (const float*)d_in[2];
    const float* gamma = (const float*)d_in[3];
    const float* beta  = (const float*)d_in[4];
    const float* W1    = (const float*)d_in[5];
    const float* b1    = (const float*)d_in[6];
    const float* W2    = (const float*)d_in[7];
    const float* b2    = (const float*)d_in[8];

    char* ws = (char*)d_ws;
    short* W0T  = (short*)(ws);
    short* W1T  = (short*)(ws + 131072);
    short* W2T  = (short*)(ws + 393216);
    int* cursor = (int*)(ws + 524288);
    int* perm   = (int*)(ws + 525312);
    short* H    = (short*)d_out;           // fp16 h aliases the fp32 output buffer
    float* out  = (float*)d_out;

    prep_kernel<<<512, 256, 0, stream>>>(W0, W1, W2, W0T, W1T, W2T, cursor);
    bucket_kernel<<<512, 256, 0, stream>>>(x, cursor, perm);
    k1_gemm_ln<<<BATCH / 64, 256, 0, stream>>>(x, b0, gamma, beta, W0T, H);
    k2_heads<<<dim3(BATCH / 64, 4), 256, 0, stream>>>(H, W1T, W2T, b1, b2, cursor, perm, out);
}

// Round 11
// 111.209 us; speedup vs baseline: 1.2932x; 1.2039x over previous
//
#include <hip/hip_runtime.h>

#define BATCH 131072
#define XDIM 260          // 256 state + 4 goal
#define SDIM 256
#define HID 256
#define HHID 128
#define ODIM 128

typedef __attribute__((ext_vector_type(8))) short short8;     // raw 16B moves
typedef __attribute__((ext_vector_type(4))) short short4v;
typedef __attribute__((ext_vector_type(4))) float floatx4;    // MFMA accum
typedef __attribute__((ext_vector_type(8))) _Float16 half8;   // f16 MFMA frag

// fp32 -> fp16 RTNE. Proven absmax 9.77e-4 (R9/R10) vs 4.22e-3 threshold.
__device__ __forceinline__ short f2h(float f) {
    union { _Float16 h; short s; } u;
    u.h = (_Float16)f;
    return u.s;
}

// ---------------------------------------------------------------------------
// prep: weights -> fp16 in MFMA-FRAGMENT order so a wave's B-frag load is one
// contiguous 1KB line-run (16 sequential cache lines) instead of 64 scattered
// lines (16B/lane at 512B stride). Index math re-derived + verified against
// the R2-proven lane mapping: frag value for lane (q=lane>>4, l15=lane&15),
// elem e is W[k = kit*32 + q*8 + e][col = c*16 + l15].
//   W0F[c:16][kit:8][lane:64][e:8]   (64KB,  c covers 256 cols)
//   W1F[g:4][c:8][kit:8][lane][e]    (256KB, c covers 128 cols, K=256)
//   W2F[g:4][c:8][kit:4][lane][e]    (128KB, K=128)
// ---------------------------------------------------------------------------
__global__ void prep_kernel(const float* __restrict__ W0, const float* __restrict__ W1,
                            const float* __restrict__ W2, short* __restrict__ W0F,
                            short* __restrict__ W1F, short* __restrict__ W2F,
                            int* __restrict__ cursor) {
    int i = blockIdx.x * 256 + threadIdx.x;   // grid 512*256 = 131072
    if (i < 4) cursor[i] = 0;
    if (i < 65536) {            // W0F
        int e = i & 7, lane = (i >> 3) & 63, kit = (i >> 9) & 7, c = (i >> 12) & 15;
        int col = c * 16 + (lane & 15);
        int k = kit * 32 + (lane >> 4) * 8 + e;
        W0F[i] = f2h(W0[k * HID + col]);
    }
    {                           // W1F (exactly 131072 elements)
        int e = i & 7, lane = (i >> 3) & 63, kit = (i >> 9) & 7, c = (i >> 12) & 7, g = i >> 15;
        int col = c * 16 + (lane & 15);
        int k = kit * 32 + (lane >> 4) * 8 + e;
        W1F[i] = f2h(W1[(g * SDIM + k) * HHID + col]);
    }
    if (i < 65536) {            // W2F
        int e = i & 7, lane = (i >> 3) & 63, kit = (i >> 9) & 3, c = (i >> 11) & 7, g = i >> 14;
        int col = c * 16 + (lane & 15);
        int k = kit * 32 + (lane >> 4) * 8 + e;
        W2F[i] = f2h(W2[(g * HHID + k) * ODIM + col]);
    }
}

// ---------------------------------------------------------------------------
// bucket: per-row argmax(goal) -> counting sort (hierarchical; R2-proven).
// ---------------------------------------------------------------------------
__global__ void bucket_kernel(const float* __restrict__ x, int* __restrict__ cursor,
                              int* __restrict__ perm) {
    __shared__ int lhist[4];
    __shared__ int lbase[4];
    const int tid = threadIdx.x;
    if (tid < 4) lhist[tid] = 0;
    __syncthreads();

    const int row = blockIdx.x * 256 + tid;
    const float4 gv = *reinterpret_cast<const float4*>(x + (size_t)row * XDIM + SDIM);
    int gi = 0; float best = gv.x;
    if (gv.y > best) { best = gv.y; gi = 1; }   // strict > keeps first max (jnp.argmax)
    if (gv.z > best) { best = gv.z; gi = 2; }
    if (gv.w > best) { best = gv.w; gi = 3; }

    const int lpos = atomicAdd(&lhist[gi], 1);
    __syncthreads();
    if (tid < 4) lbase[tid] = atomicAdd(&cursor[tid], lhist[tid]);
    __syncthreads();
    perm[gi * BATCH + lbase[gi] + lpos] = row;
}

// ---------------------------------------------------------------------------
// K1: h = LeakyReLU(LN(state @ W0 + b0)) -> fp16 H (aliases d_out, in place).
// R10's kernel with ONE delta: B-frags from fragment-ordered W0F (contiguous
// 1KB/wave loads; same values into same lanes -> arithmetic unchanged).
// ---------------------------------------------------------------------------
__global__ __launch_bounds__(256, 4) void k1_gemm_ln(
        const float* __restrict__ x, const float* __restrict__ b0,
        const float* __restrict__ gamma, const float* __restrict__ beta,
        const short* __restrict__ W0F, short* __restrict__ H) {
    __shared__ __align__(16) short a_lds[64][264];   // 256 + 8 pad
    __shared__ float psum[64][4];
    __shared__ float psq[64][4];
    __shared__ float mu_s[64];
    __shared__ float rs_s[64];

    const int tid = threadIdx.x;
    const int lane = tid & 63;
    const int w = tid >> 6;
    const int m0 = blockIdx.x * 64;

    // ---- stage x(state) fp32 -> fp16 LDS; 2 batches of 8 in-flight float4s
    #pragma unroll
    for (int half = 0; half < 2; ++half) {
        float4 v[8];
        #pragma unroll
        for (int c = 0; c < 8; ++c) {
            int s = (half * 8 + c) * 256 + tid;     // float4 slot, 64 rows x 64 slots
            int row = s >> 6;
            int k4 = (s & 63) << 2;
            v[c] = *reinterpret_cast<const float4*>(x + (size_t)(m0 + row) * XDIM + k4);
        }
        __builtin_amdgcn_sched_barrier(0);   // keep all 8 loads issued before any use
        #pragma unroll
        for (int c = 0; c < 8; ++c) {
            int s = (half * 8 + c) * 256 + tid;
            int row = s >> 6;
            int k4 = (s & 63) << 2;
            short4v sv;
            sv.x = f2h(v[c].x); sv.y = f2h(v[c].y); sv.z = f2h(v[c].z); sv.w = f2h(v[c].w);
            *reinterpret_cast<short4v*>(&a_lds[row][k4]) = sv;
        }
    }
    __syncthreads();

    const int q = lane >> 4;
    const int l15 = lane & 15;

    floatx4 acc[4][4] = {};                    // [mi][ni], rows mi*16+q*4+r, cols w*64+ni*16+l15
    const short8* B0 = reinterpret_cast<const short8*>(W0F) + (w << 11) + lane;

    #pragma unroll
    for (int kit = 0; kit < 8; ++kit) {
        half8 af[4], bf[4];
        #pragma unroll
        for (int mi = 0; mi < 4; ++mi)
            af[mi] = *reinterpret_cast<const half8*>(&a_lds[mi * 16 + l15][kit * 32 + q * 8]);
        #pragma unroll
        for (int ni = 0; ni < 4; ++ni)
            bf[ni] = *reinterpret_cast<const half8*>(&B0[(ni << 9) + (kit << 6)]);
        #pragma unroll
        for (int mi = 0; mi < 4; ++mi)
            #pragma unroll
            for (int ni = 0; ni < 4; ++ni)
                acc[mi][ni] = __builtin_amdgcn_mfma_f32_16x16x32_f16(af[mi], bf[ni], acc[mi][ni], 0, 0, 0);
    }

    // ---- + b0, LN stats (R2-proven serial-shfl reduction)
    float bias[4], gm[4], bt[4];
    #pragma unroll
    for (int ni = 0; ni < 4; ++ni) {
        int col = (w << 6) + ni * 16 + l15;
        bias[ni] = b0[col]; gm[ni] = gamma[col]; bt[ni] = beta[col];
    }
    #pragma unroll
    for (int mi = 0; mi < 4; ++mi) {
        #pragma unroll
        for (int r = 0; r < 4; ++r) {
            float s = 0.f, ss = 0.f;
            #pragma unroll
            for (int ni = 0; ni < 4; ++ni) {
                float v = acc[mi][ni][r] + bias[ni];
                acc[mi][ni][r] = v;
                s += v; ss += v * v;
            }
            #pragma unroll
            for (int off = 1; off < 16; off <<= 1) {
                s  += __shfl_xor(s,  off, 64);
                ss += __shfl_xor(ss, off, 64);
            }
            if (l15 == 0) {
                int row = mi * 16 + q * 4 + r;
                psum[row][w] = s;
                psq[row][w]  = ss;
            }
        }
    }
    __syncthreads();
    if (tid < 64) {
        float s  = psum[tid][0] + psum[tid][1] + psum[tid][2] + psum[tid][3];
        float ss = psq[tid][0]  + psq[tid][1]  + psq[tid][2]  + psq[tid][3];
        float mu = s * (1.f / 256.f);
        float var = ss * (1.f / 256.f) - mu * mu;
        mu_s[tid] = mu;
        rs_s[tid] = rsqrtf(var + 1e-5f);
    }
    __syncthreads();

    // ---- normalize + leaky + store fp16 (R2-proven scalar store epilogue)
    #pragma unroll
    for (int mi = 0; mi < 4; ++mi) {
        #pragma unroll
        for (int r = 0; r < 4; ++r) {
            int row = mi * 16 + q * 4 + r;
            float mu = mu_s[row], rs = rs_s[row];
            short* dst = H + (size_t)(m0 + row) * HID + (w << 6) + l15;
            #pragma unroll
            for (int ni = 0; ni < 4; ++ni) {
                float v = (acc[mi][ni][r] - mu) * rs * gm[ni] + bt[ni];
                v = (v >= 0.f) ? v : 0.1f * v;
                dst[ni * 16] = f2h(v);
            }
        }
    }
}

// ---------------------------------------------------------------------------
// K2: per (goal g, 64-row tile): t = relu(h @ W1[g] + b1[g]); out = t @ W2[g] + b2[g]
// H aliases out row-in-place (R2-proven race-free). ONE delta vs R10:
// B-frags from fragment-ordered W1F/W2F (contiguous 1KB/wave loads).
// ---------------------------------------------------------------------------
__global__ __launch_bounds__(256, 2) void k2_heads(
        const short* H, const short* __restrict__ W1F, const short* __restrict__ W2F,
        const float* __restrict__ b1, const float* __restrict__ b2,
        const int* __restrict__ cursor, const int* __restrict__ perm,
        float* out) {
    const int g = blockIdx.y;
    const int t = blockIdx.x;
    const int cnt = cursor[g];
    if (t * 64 >= cnt) return;

    __shared__ __align__(16) short a_lds[64][264];
    __shared__ __align__(16) short t_lds[64][136];
    __shared__ int rows_s[64];

    const int tid = threadIdx.x;
    const int lane = tid & 63;
    const int w = tid >> 6;
    const int* pg = perm + (size_t)g * BATCH;

    if (tid < 64) {
        int idx = t * 64 + tid;
        rows_s[tid] = pg[idx < cnt ? idx : cnt - 1];
    }
    __syncthreads();

    // ---- gather h rows (fp16), coalesced 16B/lane
    #pragma unroll
    for (int c = 0; c < 8; ++c) {
        int s = c * 256 + tid;                 // 16B slot, 64 rows x 32 slots
        int row = s >> 5;
        int k8 = (s & 31) << 3;
        short8 v = *reinterpret_cast<const short8*>(H + (size_t)rows_s[row] * HID + k8);
        *reinterpret_cast<short8*>(&a_lds[row][k8]) = v;
    }
    __syncthreads();

    const int q = lane >> 4;
    const int l15 = lane & 15;

    // ---- GEMM1: 64x128, K=256; wave w owns cols [w*32, w*32+32)
    floatx4 acc1[4][2] = {};
    const short8* B1 = reinterpret_cast<const short8*>(W1F) + (g << 12) + (w << 10) + lane;
    #pragma unroll
    for (int kit = 0; kit < 8; ++kit) {
        half8 af[4], bf[2];
        #pragma unroll
        for (int mi = 0; mi < 4; ++mi)
            af[mi] = *reinterpret_cast<const half8*>(&a_lds[mi * 16 + l15][kit * 32 + q * 8]);
        #pragma unroll
        for (int ni = 0; ni < 2; ++ni)
            bf[ni] = *reinterpret_cast<const half8*>(&B1[(ni << 9) + (kit << 6)]);
        #pragma unroll
        for (int mi = 0; mi < 4; ++mi)
            #pragma unroll
            for (int ni = 0; ni < 2; ++ni)
                acc1[mi][ni] = __builtin_amdgcn_mfma_f32_16x16x32_f16(af[mi], bf[ni], acc1[mi][ni], 0, 0, 0);
    }
    // bias + relu -> t_lds (fp16)
    #pragma unroll
    for (int ni = 0; ni < 2; ++ni) {
        int col = (w << 5) + ni * 16 + l15;
        float bb = b1[g * HHID + col];
        #pragma unroll
        for (int mi = 0; mi < 4; ++mi)
            #pragma unroll
            for (int r = 0; r < 4; ++r) {
                int row = mi * 16 + q * 4 + r;
                float v = acc1[mi][ni][r] + bb;
                t_lds[row][col] = f2h(v > 0.f ? v : 0.f);
            }
    }
    __syncthreads();

    // ---- GEMM2: 64x128, K=128
    floatx4 acc2[4][2] = {};
    const short8* B2 = reinterpret_cast<const short8*>(W2F) + (g << 11) + (w << 9) + lane;
    #pragma unroll
    for (int kit = 0; kit < 4; ++kit) {
        half8 af[4], bf[2];
        #pragma unroll
        for (int mi = 0; mi < 4; ++mi)
            af[mi] = *reinterpret_cast<const half8*>(&t_lds[mi * 16 + l15][kit * 32 + q * 8]);
        #pragma unroll
        for (int ni = 0; ni < 2; ++ni)
            bf[ni] = *reinterpret_cast<const half8*>(&B2[(ni << 8) + (kit << 6)]);
        #pragma unroll
        for (int mi = 0; mi < 4; ++mi)
            #pragma unroll
            for (int ni = 0; ni < 2; ++ni)
                acc2[mi][ni] = __builtin_amdgcn_mfma_f32_16x16x32_f16(af[mi], bf[ni], acc2[mi][ni], 0, 0, 0);
    }
    // bias + scatter out (fp32)
    #pragma unroll
    for (int ni = 0; ni < 2; ++ni) {
        int col = (w << 5) + ni * 16 + l15;
        float bb = b2[g * ODIM + col];
        #pragma unroll
        for (int mi = 0; mi < 4; ++mi)
            #pragma unroll
            for (int r = 0; r < 4; ++r) {
                int row = mi * 16 + q * 4 + r;
                int idx = t * 64 + row;
                if (idx < cnt)
                    out[(size_t)rows_s[row] * ODIM + col] = acc2[mi][ni][r] + bb;
            }
    }
}

// ---------------------------------------------------------------------------
// workspace layout (2.62 MB):
//   [0, 131072)            W0F fp16 (fragment-ordered)
//   [131072, 393216)       W1F fp16
//   [393216, 524288)       W2F fp16
//   [524288, 524304)       cursor (padded to 1024)
//   [525312, 2622464)      perm (4 x 131072 int)
// h (fp16, 64 MB) lives in d_out (row-in-place; one owner block per row).
// ---------------------------------------------------------------------------
extern "C" void kernel_launch(void* const* d_in, const int* in_sizes, int n_in,
                              void* d_out, int out_size, void* d_ws, size_t ws_size,
                              hipStream_t stream) {
    const float* x     = (const float*)d_in[0];
    const float* W0    = (const float*)d_in[1];
    const float* b0    = (const float*)d_in[2];
    const float* gamma = (const float*)d_in[3];
    const float* beta  = (const float*)d_in[4];
    const float* W1    = (const float*)d_in[5];
    const float* b1    = (const float*)d_in[6];
    const float* W2    = (const float*)d_in[7];
    const float* b2    = (const float*)d_in[8];

    char* ws = (char*)d_ws;
    short* W0F  = (short*)(ws);
    short* W1F  = (short*)(ws + 131072);
    short* W2F  = (short*)(ws + 393216);
    int* cursor = (int*)(ws + 524288);
    int* perm   = (int*)(ws + 525312);
    short* H    = (short*)d_out;           // fp16 h aliases the fp32 output buffer
    float* out  = (float*)d_out;

    prep_kernel<<<512, 256, 0, stream>>>(W0, W1, W2, W0F, W1F, W2F, cursor);
    bucket_kernel<<<512, 256, 0, stream>>>(x, cursor, perm);
    k1_gemm_ln<<<BATCH / 64, 256, 0, stream>>>(x, b0, gamma, beta, W0F, H);
    k2_heads<<<dim3(BATCH / 64, 4), 256, 0, stream>>>(H, W1F, W2F, b1, b2, cursor, perm, out);
}